// Round 1
// baseline (1059.361 us; speedup 1.0000x reference)
//
#include <hip/hip_runtime.h>
#include <stdint.h>

typedef unsigned short u16;
typedef unsigned int   u32;
typedef float  f32x4 __attribute__((ext_vector_type(4)));
typedef u32    u32x4 __attribute__((ext_vector_type(4)));
typedef short  s16x8 __attribute__((ext_vector_type(8)));

#define NODES 16384
#define BGR   64
#define PG    256
#define HDIM  512
#define INDIM 4096
#define CCL   12

__device__ __forceinline__ float bf2f(u16 u){ u32 x = ((u32)u) << 16; return __uint_as_float(x); }
__device__ __forceinline__ u16 f2bf(float f){
    u32 x = __float_as_uint(f);
    return (u16)((x + 0x7fffu + ((x >> 16) & 1u)) >> 16);
}
__device__ __forceinline__ u32 pk2(float a, float b){ return (u32)f2bf(a) | ((u32)f2bf(b) << 16); }

// ---------------- transpose + fp32->bf16:  Wt[n][k] = bf16(W[k][n]) ----------------
__global__ void transpose_bf16(const float* __restrict__ W, u16* __restrict__ Wt, int K, int N){
    __shared__ float tile[32][33];
    int k0 = blockIdx.x * 32, n0 = blockIdx.y * 32;
    int tx = threadIdx.x, ty = threadIdx.y;      // (32,8)
    #pragma unroll
    for (int j = 0; j < 4; ++j)
        tile[ty + 8*j][tx] = W[(size_t)(k0 + ty + 8*j) * N + n0 + tx];
    __syncthreads();
    #pragma unroll
    for (int j = 0; j < 4; ++j)
        Wt[(size_t)(n0 + ty + 8*j) * K + k0 + tx] = f2bf(tile[tx][ty + 8*j]);
}

// ---------------- build dense per-graph adjacency (counts) ----------------
__global__ void build_adj(const int* __restrict__ ei, float* __restrict__ adj, int E){
    int e = blockIdx.x * 256 + threadIdx.x;
    if (e < E){
        int s = ei[e];
        int d = ei[E + e];
        // adj[b][ps][pd] flat = (b*256+ps)*256+pd = s*256 + (d&255)
        atomicAdd(&adj[(size_t)s * 256 + (d & 255)], 1.0f);
    }
}

// ---------------- row sums -> degrees (DMoN) and dinv (GCN, +1 self loop) ----------------
__global__ void rowsum_deg(const float* __restrict__ adj, float* __restrict__ degs,
                           float* __restrict__ dinv){
    int r = blockIdx.x * 4 + (threadIdx.x >> 6);
    int lane = threadIdx.x & 63;
    const float* row = adj + (size_t)r * 256;
    float s = row[lane] + row[lane + 64] + row[lane + 128] + row[lane + 192];
    #pragma unroll
    for (int m = 1; m < 64; m <<= 1) s += __shfl_xor(s, m);
    if (lane == 0){ degs[r] = s; dinv[r] = 1.0f / sqrtf(s + 1.0f); }
}

// ---------------- bf16 MFMA GEMM, 128x128 tile, BK=32 ----------------
// AF32=1: A fp32 (convert during staging). EPI=0: out = bf16(rowscale[r]*acc)
// EPI=1: out = bf16(acc + bias[c])
template<int AF32, int EPI>
__global__ __launch_bounds__(256, 2) void gemm_bf16(
    const void* __restrict__ Ap, const u16* __restrict__ Bt, u16* __restrict__ Out,
    const float* __restrict__ rowscale, const float* __restrict__ bias,
    int M, int N, int K, int ntn)
{
    int bid = blockIdx.x;
    int m0 = (bid / ntn) * 128, n0 = (bid % ntn) * 128;
    int t = threadIdx.x, lane = t & 63, w = t >> 6;
    int wr = (w >> 1) * 64, wc = (w & 1) * 64;

    __shared__ __align__(16) u16 a_l[128][40];
    __shared__ __align__(16) u16 b_l[128][40];

    f32x4 acc[4][4];
    #pragma unroll
    for (int m = 0; m < 4; ++m)
        #pragma unroll
        for (int n = 0; n < 4; ++n) acc[m][n] = (f32x4)0.0f;

    int row = t >> 1, kseg = (t & 1) * 16;
    int r16 = lane & 15, khalf = (lane >> 4) * 8;

    for (int k0 = 0; k0 < K; k0 += 32){
        __syncthreads();
        // stage A tile (128 x 32)
        if (AF32){
            const f32x4* A = (const f32x4*)((const float*)Ap + (size_t)(m0 + row) * K + k0 + kseg);
            f32x4 f0 = A[0], f1 = A[1], f2 = A[2], f3 = A[3];
            u32x4 w0 = { pk2(f0.x, f0.y), pk2(f0.z, f0.w), pk2(f1.x, f1.y), pk2(f1.z, f1.w) };
            u32x4 w1 = { pk2(f2.x, f2.y), pk2(f2.z, f2.w), pk2(f3.x, f3.y), pk2(f3.z, f3.w) };
            *(u32x4*)&a_l[row][kseg]     = w0;
            *(u32x4*)&a_l[row][kseg + 8] = w1;
        } else {
            const u32x4* A = (const u32x4*)((const u16*)Ap + (size_t)(m0 + row) * K + k0 + kseg);
            *(u32x4*)&a_l[row][kseg]     = A[0];
            *(u32x4*)&a_l[row][kseg + 8] = A[1];
        }
        // stage B tile (128 cols x 32 k), Bt is [N][K]
        {
            const u32x4* B = (const u32x4*)(Bt + (size_t)(n0 + row) * K + k0 + kseg);
            *(u32x4*)&b_l[row][kseg]     = B[0];
            *(u32x4*)&b_l[row][kseg + 8] = B[1];
        }
        __syncthreads();

        s16x8 af[4], bf[4];
        #pragma unroll
        for (int m = 0; m < 4; ++m) af[m] = *(const s16x8*)&a_l[wr + m*16 + r16][khalf];
        #pragma unroll
        for (int n = 0; n < 4; ++n) bf[n] = *(const s16x8*)&b_l[wc + n*16 + r16][khalf];
        #pragma unroll
        for (int m = 0; m < 4; ++m)
            #pragma unroll
            for (int n = 0; n < 4; ++n)
                acc[m][n] = __builtin_amdgcn_mfma_f32_16x16x32_bf16(af[m], bf[n], acc[m][n], 0, 0, 0);
    }

    int r4 = (lane >> 4) * 4, c16 = lane & 15;
    #pragma unroll
    for (int m = 0; m < 4; ++m)
        #pragma unroll
        for (int n = 0; n < 4; ++n)
            #pragma unroll
            for (int r = 0; r < 4; ++r){
                int gr = m0 + wr + m*16 + r4 + r;
                int gc = n0 + wc + n*16 + c16;
                float v = acc[m][n][r];
                if (EPI == 0) v *= rowscale[gr];
                else          v += bias[gc];
                Out[(size_t)gr * N + gc] = f2bf(v);
            }
}

// ---------------- GCN sparse aggregation: h1 = relu(dinv_i*(A_row_i@hs + hs_i) + b1), bf16 out
__global__ void gcn_agg(const float* __restrict__ adj, const u16* __restrict__ hs,
                        const float* __restrict__ dinv, const float* __restrict__ b1,
                        u16* __restrict__ h1){
    int i = blockIdx.x, t = threadIdx.x;
    __shared__ float arow[256];
    arow[t] = adj[(size_t)i * 256 + t];
    __syncthreads();
    int gb = i & ~255;
    float a0 = 0.f, a1 = 0.f;
    const u16* hsg = hs + (size_t)gb * 512 + 2 * t;
    for (int j = 0; j < 256; ++j){
        float a = arow[j];                 // uniform across block -> cheap skip
        if (a != 0.f){
            u32 hv = *(const u32*)(hsg + (size_t)j * 512);
            a0 += a * bf2f((u16)(hv & 0xffff));
            a1 += a * bf2f((u16)(hv >> 16));
        }
    }
    u32 hv = *(const u32*)(hs + (size_t)i * 512 + 2 * t);
    a0 += bf2f((u16)(hv & 0xffff));
    a1 += bf2f((u16)(hv >> 16));
    float di = dinv[i];
    float v0 = fmaxf(di * a0 + b1[2*t],     0.f);
    float v1 = fmaxf(di * a1 + b1[2*t + 1], 0.f);
    *(u32*)(h1 + (size_t)i * 512 + 2 * t) = (u32)f2bf(v0) | ((u32)f2bf(v1) << 16);
}

// ---------------- sel = softmax(t1 @ Wm2 + bm2), one wave per node ----------------
__global__ void sel_kernel(const u16* __restrict__ t1, const float* __restrict__ Wm2,
                           const float* __restrict__ bm2, float* __restrict__ sel){
    int n = blockIdx.x * 4 + (threadIdx.x >> 6);
    int lane = threadIdx.x & 63;
    u32x4 v = *(const u32x4*)(t1 + (size_t)n * 512 + lane * 8);
    float tv[8];
    tv[0]=bf2f((u16)(v.x&0xffff)); tv[1]=bf2f((u16)(v.x>>16));
    tv[2]=bf2f((u16)(v.y&0xffff)); tv[3]=bf2f((u16)(v.y>>16));
    tv[4]=bf2f((u16)(v.z&0xffff)); tv[5]=bf2f((u16)(v.z>>16));
    tv[6]=bf2f((u16)(v.w&0xffff)); tv[7]=bf2f((u16)(v.w>>16));
    float acc[CCL];
    #pragma unroll
    for (int c = 0; c < CCL; ++c) acc[c] = 0.f;
    #pragma unroll
    for (int i = 0; i < 8; ++i){
        const float* wr = Wm2 + (size_t)(lane * 8 + i) * CCL;
        #pragma unroll
        for (int c = 0; c < CCL; ++c) acc[c] += tv[i] * wr[c];
    }
    #pragma unroll
    for (int m = 1; m < 64; m <<= 1)
        #pragma unroll
        for (int c = 0; c < CCL; ++c) acc[c] += __shfl_xor(acc[c], m);
    if (lane == 0){
        float mx = -1e30f;
        #pragma unroll
        for (int c = 0; c < CCL; ++c){ acc[c] += bm2[c]; mx = fmaxf(mx, acc[c]); }
        float s = 0.f;
        #pragma unroll
        for (int c = 0; c < CCL; ++c){ acc[c] = expf(acc[c] - mx); s += acc[c]; }
        float inv = 1.f / s;
        #pragma unroll
        for (int c = 0; c < CCL; ++c) sel[(size_t)n * CCL + c] = acc[c] * inv;
    }
}

__device__ __forceinline__ float selu(float x){
    const float sc = 1.0507009873554804934193349852946f;
    const float al = 1.6732632423543772848170429916717f;
    return x > 0.f ? sc * x : sc * al * (expf(x) - 1.f);
}

// ---------------- out[b][c][h] = selu(sum_n sel[n][c]*h1[n][h]) ----------------
__global__ void out_kernel(const float* __restrict__ sel, const u16* __restrict__ h1,
                           float* __restrict__ outp){
    int b = blockIdx.x >> 2, hb = blockIdx.x & 3;
    int t = threadIdx.x;   // 128
    __shared__ float sel_l[PG * CCL];
    for (int i = t; i < PG * CCL; i += 128) sel_l[i] = sel[(size_t)b * PG * CCL + i];
    __syncthreads();
    int h = hb * 128 + t;
    float acc[CCL];
    #pragma unroll
    for (int c = 0; c < CCL; ++c) acc[c] = 0.f;
    const u16* hp = h1 + (size_t)b * PG * 512 + h;
    for (int n = 0; n < PG; ++n){
        float v = bf2f(hp[(size_t)n * 512]);
        const float* s = sel_l + n * CCL;
        #pragma unroll
        for (int c = 0; c < CCL; ++c) acc[c] += v * s[c];
    }
    #pragma unroll
    for (int c = 0; c < CCL; ++c)
        outp[((size_t)b * CCL + c) * 512 + h] = selu(acc[c]);
}

// ---------------- per-graph pooling losses + normalized coarse adjacency ----------------
__global__ void pool_kernel(const float* __restrict__ sel, const float* __restrict__ adj,
                            const float* __restrict__ degs, float* __restrict__ oan,
                            float* __restrict__ scal){
    int b = blockIdx.x, t = threadIdx.x;   // 256
    __shared__ float sel_l[PG * CCL];
    __shared__ float u_l[PG * CCL];
    __shared__ float deg_l[PG];
    __shared__ float ss_l[144], oa_l[144];
    __shared__ float ca_l[CCL], cs_l[CCL], rs_l[CCL];
    __shared__ float msum;
    for (int i = t; i < PG * CCL; i += 256) sel_l[i] = sel[(size_t)b * PG * CCL + i];
    deg_l[t] = degs[b * PG + t];
    __syncthreads();
    {   // u = adj @ sel  via symmetry: u[t][c] = sum_j adj[j][t]*sel[j][c]  (coalesced)
        float u[CCL];
        #pragma unroll
        for (int c = 0; c < CCL; ++c) u[c] = 0.f;
        const float* adjb = adj + (size_t)b * PG * PG;
        for (int j = 0; j < PG; ++j){
            float a = adjb[j * PG + t];
            const float* s = sel_l + j * CCL;
            #pragma unroll
            for (int c = 0; c < CCL; ++c) u[c] += a * s[c];
        }
        #pragma unroll
        for (int c = 0; c < CCL; ++c) u_l[t * CCL + c] = u[c];
    }
    __syncthreads();
    if (t < 144){
        int c = t / 12, k = t % 12;
        float ssv = 0.f, oav = 0.f;
        for (int n = 0; n < PG; ++n){
            ssv += sel_l[n * CCL + c] * sel_l[n * CCL + k];
            oav += sel_l[n * CCL + c] * u_l[n * CCL + k];
        }
        ss_l[t] = ssv; oa_l[t] = oav;
    } else if (t < 156){
        int c = t - 144; float cs = 0.f, ca = 0.f;
        for (int n = 0; n < PG; ++n){
            float s = sel_l[n * CCL + c];
            cs += s; ca += s * deg_l[n];
        }
        cs_l[c] = cs; ca_l[c] = ca;
    } else if (t == 156){
        float s = 0.f;
        for (int n = 0; n < PG; ++n) s += deg_l[n];
        msum = s;
    }
    __syncthreads();
    if (t == 0){
        float m = msum * 0.5f;
        float inv2m = 1.f / (2.f * m);
        float sp = 0.f;
        for (int c = 0; c < CCL; ++c) sp += oa_l[c * 13] - ca_l[c] * ca_l[c] * inv2m;
        scal[b] = -sp * inv2m;                                   // spectral_b
        float s2 = 0.f;
        for (int i = 0; i < 144; ++i) s2 += ss_l[i] * ss_l[i];
        float ssn = sqrtf(s2);
        const float isq = 0.28867513459481288f;                  // 1/sqrt(12)
        float o2 = 0.f;
        for (int i = 0; i < 144; ++i){
            float d = ss_l[i] / ssn - ((i % 13 == 0) ? isq : 0.f);
            o2 += d * d;
        }
        scal[64 + b] = sqrtf(o2);                                // ortho_b
        float c2 = 0.f;
        for (int c = 0; c < CCL; ++c) c2 += cs_l[c] * cs_l[c];
        scal[128 + b] = sqrtf(c2) * (sqrtf(12.f) / 256.f) - 1.f; // cluster_b
    }
    if (t < CCL){
        float r = 0.f;
        for (int k = 0; k < CCL; ++k) if (k != t) r += oa_l[t * CCL + k];
        rs_l[t] = sqrtf(r) + 1e-15f;
    }
    __syncthreads();
    if (t < 144){
        int c = t / 12, k = t % 12;
        float v = (c == k) ? 0.f : oa_l[t] / (rs_l[c] * rs_l[k]);
        oan[(size_t)b * 144 + t] = v;
    }
}

// ---------------- head: g = mean_c(h2), MLP, logits ----------------
__global__ void head_kernel(const float* __restrict__ outp, const float* __restrict__ oan,
                            const float* __restrict__ Wrel, const float* __restrict__ brel,
                            const float* __restrict__ Wroot,
                            const float* __restrict__ Wl1, const float* __restrict__ bl1,
                            const float* __restrict__ Wl2, const float* __restrict__ bl2,
                            float* __restrict__ dout){
    int b = blockIdx.x, t = threadIdx.x;  // 256
    __shared__ float out_l[CCL * 512];
    __shared__ float w12[CCL];
    __shared__ float v1l[512], v2l[512], gprel[512], gl[512];
    for (int i = t; i < CCL * 512; i += 256) out_l[i] = outp[(size_t)b * CCL * 512 + i];
    if (t < CCL){
        float s = 0.f;
        for (int c = 0; c < CCL; ++c) s += oan[(size_t)b * 144 + c * CCL + t];
        w12[t] = s * (1.f / 12.f);
    }
    __syncthreads();
    for (int h = t; h < 512; h += 256){
        float a1 = 0.f, a2 = 0.f;
        #pragma unroll
        for (int k = 0; k < CCL; ++k){ a1 += w12[k] * out_l[k * 512 + h]; a2 += out_l[k * 512 + h]; }
        v1l[h] = a1; v2l[h] = a2 * (1.f / 12.f);
    }
    __syncthreads();
    for (int h = t; h < 512; h += 256){
        float acc = brel[h];
        for (int k = 0; k < 512; ++k)
            acc += v1l[k] * Wrel[(size_t)k * 512 + h] + v2l[k] * Wroot[(size_t)k * 512 + h];
        gprel[h] = acc;
    }
    __syncthreads();
    for (int h = t; h < 512; h += 256){
        float acc = bl1[h];
        for (int k = 0; k < 512; ++k) acc += gprel[k] * Wl1[(size_t)k * 512 + h];
        gl[h] = fmaxf(acc, 0.f);
    }
    __syncthreads();
    if (t < 64){
        float acc[5] = {0.f, 0.f, 0.f, 0.f, 0.f};
        for (int h = t; h < 512; h += 64){
            float g = gl[h];
            #pragma unroll
            for (int o = 0; o < 5; ++o) acc[o] += g * Wl2[(size_t)h * 5 + o];
        }
        #pragma unroll
        for (int m = 1; m < 64; m <<= 1)
            #pragma unroll
            for (int o = 0; o < 5; ++o) acc[o] += __shfl_xor(acc[o], m);
        if (t == 0){
            #pragma unroll
            for (int o = 0; o < 5; ++o) dout[b * 5 + o] = acc[o] + bl2[o];
        }
    }
}

__global__ void loss_kernel(const float* __restrict__ scal, float* __restrict__ dout){
    int t = threadIdx.x;  // 64
    float v = scal[t] + scal[64 + t] + scal[128 + t];
    #pragma unroll
    for (int m = 1; m < 64; m <<= 1) v += __shfl_xor(v, m);
    if (t == 0) dout[BGR * 5] = v * (1.f / 64.f);
}

extern "C" void kernel_launch(void* const* d_in, const int* in_sizes, int n_in,
                              void* d_out, int out_size, void* d_ws, size_t ws_size,
                              hipStream_t stream)
{
    const float* x    = (const float*)d_in[0];
    const int*   ei   = (const int*)d_in[1];
    const float* W1   = (const float*)d_in[3];
    const float* b1   = (const float*)d_in[4];
    const float* Wm1  = (const float*)d_in[5];
    const float* bm1  = (const float*)d_in[6];
    const float* Wm2  = (const float*)d_in[7];
    const float* bm2  = (const float*)d_in[8];
    const float* Wrel = (const float*)d_in[9];
    const float* brel = (const float*)d_in[10];
    const float* Wroot= (const float*)d_in[11];
    const float* Wl1  = (const float*)d_in[12];
    const float* bl1  = (const float*)d_in[13];
    const float* Wl2  = (const float*)d_in[14];
    const float* bl2  = (const float*)d_in[15];
    float* dout = (float*)d_out;
    const int E = in_sizes[1] / 2;

    char* w = (char*)d_ws;
    float* adj  = (float*)(w + 0);            // 16,777,216 B
    float* degs = (float*)(w + 16777216);     // 65,536 B
    float* dinv = (float*)(w + 16842752);     // 65,536 B
    u16*   Wt   = (u16*)  (w + 16908288);     // 4 MiB (reused below after GEMM1)
    u16*   Wm1t = (u16*)  (w + 21102592);     // 512 KiB
    u16*   hs   = (u16*)  (w + 21626880);     // 16 MiB (reused as t1 after gcn_agg)
    u16*   h1   = (u16*)  (w + 38404096);     // 16 MiB
    // Wt region reuse (GEMM1 finished before these are written):
    float* sel  = (float*)(w + 16908288);                       // 786,432 B
    float* outp = (float*)(w + 16908288 + 786432);              // 1,572,864 B
    float* oan  = (float*)(w + 16908288 + 786432 + 1572864);    // 36,864 B
    float* scal = (float*)(w + 16908288 + 786432 + 1572864 + 36864); // 768 B
    u16* t1 = hs;

    hipMemsetAsync(adj, 0, 16777216, stream);

    hipLaunchKernelGGL(transpose_bf16, dim3(INDIM / 32, HDIM / 32), dim3(32, 8), 0, stream,
                       W1, Wt, INDIM, HDIM);
    hipLaunchKernelGGL(transpose_bf16, dim3(HDIM / 32, HDIM / 32), dim3(32, 8), 0, stream,
                       Wm1, Wm1t, HDIM, HDIM);
    hipLaunchKernelGGL(build_adj, dim3((E + 255) / 256), dim3(256), 0, stream, ei, adj, E);
    hipLaunchKernelGGL(rowsum_deg, dim3(NODES / 4), dim3(256), 0, stream, adj, degs, dinv);
    // hs = bf16(dinv_row * (x @ W1))
    hipLaunchKernelGGL((gemm_bf16<1, 0>), dim3((NODES / 128) * 4), dim3(256), 0, stream,
                       (const void*)x, Wt, hs, dinv, (const float*)nullptr,
                       NODES, HDIM, INDIM, 4);
    hipLaunchKernelGGL(gcn_agg, dim3(NODES), dim3(256), 0, stream, adj, hs, dinv, b1, h1);
    // t1 = bf16(h1 @ Wm1 + bm1)   (t1 aliases hs; hs no longer needed)
    hipLaunchKernelGGL((gemm_bf16<0, 1>), dim3((NODES / 128) * 4), dim3(256), 0, stream,
                       (const void*)h1, Wm1t, t1, (const float*)nullptr, bm1,
                       NODES, HDIM, HDIM, 4);
    hipLaunchKernelGGL(sel_kernel, dim3(NODES / 4), dim3(256), 0, stream, t1, Wm2, bm2, sel);
    hipLaunchKernelGGL(out_kernel, dim3(BGR * 4), dim3(128), 0, stream, sel, h1, outp);
    hipLaunchKernelGGL(pool_kernel, dim3(BGR), dim3(256), 0, stream, sel, adj, degs, oan, scal);
    hipLaunchKernelGGL(head_kernel, dim3(BGR), dim3(256), 0, stream, outp, oan,
                       Wrel, brel, Wroot, Wl1, bl1, Wl2, bl2, dout);
    hipLaunchKernelGGL(loss_kernel, dim3(1), dim3(64), 0, stream, scal, dout);
}

// Round 2
// 866.187 us; speedup vs baseline: 1.2230x; 1.2230x over previous
//
#include <hip/hip_runtime.h>
#include <stdint.h>

typedef unsigned short u16;
typedef unsigned int   u32;
typedef float  f32x4 __attribute__((ext_vector_type(4)));
typedef u32    u32x2 __attribute__((ext_vector_type(2)));
typedef u32    u32x4 __attribute__((ext_vector_type(4)));
typedef short  s16x8 __attribute__((ext_vector_type(8)));

#define NODES 16384
#define BGR   64
#define PG    256
#define HDIM  512
#define INDIM 4096
#define CCL   12

__device__ __forceinline__ float bf2f(u16 u){ u32 x = ((u32)u) << 16; return __uint_as_float(x); }
__device__ __forceinline__ u16 f2bf(float f){
    u32 x = __float_as_uint(f);
    return (u16)((x + 0x7fffu + ((x >> 16) & 1u)) >> 16);
}
__device__ __forceinline__ u32 pk2(float a, float b){ return (u32)f2bf(a) | ((u32)f2bf(b) << 16); }

// ---------------- transpose + fp32->bf16:  Wt[n][k] = bf16(W[k][n]) ----------------
__global__ void transpose_bf16(const float* __restrict__ W, u16* __restrict__ Wt, int K, int N){
    __shared__ float tile[32][33];
    int k0 = blockIdx.x * 32, n0 = blockIdx.y * 32;
    int tx = threadIdx.x, ty = threadIdx.y;      // (32,8)
    #pragma unroll
    for (int j = 0; j < 4; ++j)
        tile[ty + 8*j][tx] = W[(size_t)(k0 + ty + 8*j) * N + n0 + tx];
    __syncthreads();
    #pragma unroll
    for (int j = 0; j < 4; ++j)
        Wt[(size_t)(n0 + ty + 8*j) * K + k0 + tx] = f2bf(tile[tx][ty + 8*j]);
}

// ---------------- u16 transpose: out[c][r] = in[r][c] ----------------
__global__ void transpose_u16(const u16* __restrict__ in, u16* __restrict__ out, int R, int C){
    __shared__ u16 tile[32][33];
    int r0 = blockIdx.x * 32, c0 = blockIdx.y * 32;
    int tx = threadIdx.x, ty = threadIdx.y;      // (32,8)
    #pragma unroll
    for (int j = 0; j < 4; ++j)
        tile[ty + 8*j][tx] = in[(size_t)(r0 + ty + 8*j) * C + c0 + tx];
    __syncthreads();
    #pragma unroll
    for (int j = 0; j < 4; ++j)
        out[(size_t)(c0 + ty + 8*j) * R + r0 + tx] = tile[tx][ty + 8*j];
}

// ---------------- build dense per-graph adjacency (counts) ----------------
__global__ void build_adj(const int* __restrict__ ei, float* __restrict__ adj, int E){
    int e = blockIdx.x * 256 + threadIdx.x;
    if (e < E){
        int s = ei[e];
        int d = ei[E + e];
        atomicAdd(&adj[(size_t)s * 256 + (d & 255)], 1.0f);
    }
}

// ---------------- row sums -> degrees (DMoN) and dinv (GCN, +1 self loop) ----------------
__global__ void rowsum_deg(const float* __restrict__ adj, float* __restrict__ degs,
                           float* __restrict__ dinv){
    int r = blockIdx.x * 4 + (threadIdx.x >> 6);
    int lane = threadIdx.x & 63;
    const float* row = adj + (size_t)r * 256;
    float s = row[lane] + row[lane + 64] + row[lane + 128] + row[lane + 192];
    #pragma unroll
    for (int m = 1; m < 64; m <<= 1) s += __shfl_xor(s, m);
    if (lane == 0){ degs[r] = s; dinv[r] = 1.0f / sqrtf(s + 1.0f); }
}

// ---------------- unified bf16 MFMA GEMM: 64(M) x 512(N) tile, BK=32, dbuf LDS ----------------
// AF32: A is fp32 (convert in staging). EPI: 0 = rowscale[r]*acc
//                                            1 = acc + bias[c]
//                                            2 = relu(rowscale[r]*(acc + aux[r][c]) + bias[c])
template<int AF32, int EPI>
__global__ __launch_bounds__(512, 1) void gemm512(
    const void* __restrict__ Ap, int lda, int abstride,
    const u16* __restrict__ Bt, int ldb, int btstride,
    u16* __restrict__ Out,
    const float* __restrict__ rowscale, const float* __restrict__ bias,
    const u16* __restrict__ aux, int K, int prows)
{
    int m0l = blockIdx.x * 64;
    int g   = blockIdx.y;
    int t = threadIdx.x, lane = t & 63, w = t >> 6;
    int wc = w * 64;
    int grow0 = g * prows + m0l;

    __shared__ __align__(16) u16 a_l[2][64][40];
    __shared__ __align__(16) u16 b_l[2][512][40];

    f32x4 acc[4][4];
    #pragma unroll
    for (int m = 0; m < 4; ++m)
        #pragma unroll
        for (int n = 0; n < 4; ++n) acc[m][n] = (f32x4)0.0f;

    const float* A32 = (const float*)Ap + (size_t)g * abstride;
    const u16*   A16 = (const u16*)Ap + (size_t)g * abstride;
    const u16*   Bp  = Bt + (size_t)g * btstride;

    int arow = t >> 3, acol = (t & 7) * 4;          // A tile 64x32, 4 elems/thread
    int r16 = lane & 15, khalf = (lane >> 4) * 8;
    const int nt = K / 32;

    f32x4 raf0, raf1; u32x2 rah0, rah1; u32x4 rb0[4], rb1[4];

#define LOAD_TILE(S, kt) do {                                                        \
    int k0_ = (kt) * 32;                                                             \
    if (AF32) raf##S = *(const f32x4*)(A32 + (size_t)(m0l + arow) * lda + k0_ + acol);\
    else      rah##S = *(const u32x2*)(A16 + (size_t)(m0l + arow) * lda + k0_ + acol);\
    const u16* bp_ = Bp + (size_t)t * ldb + k0_;                                     \
    _Pragma("unroll")                                                                \
    for (int j_ = 0; j_ < 4; ++j_) rb##S[j_] = *(const u32x4*)(bp_ + j_ * 8);        \
} while (0)

#define STORE_TILE(S, buf) do {                                                      \
    u32x2 aw_;                                                                       \
    if (AF32) { aw_.x = pk2(raf##S.x, raf##S.y); aw_.y = pk2(raf##S.z, raf##S.w); }  \
    else aw_ = rah##S;                                                               \
    *(u32x2*)&a_l[buf][arow][acol] = aw_;                                            \
    _Pragma("unroll")                                                                \
    for (int j_ = 0; j_ < 4; ++j_) *(u32x4*)&b_l[buf][t][j_ * 8] = rb##S[j_];        \
} while (0)

#define COMPUTE(buf) do {                                                            \
    s16x8 af_[4], bf_[4];                                                            \
    _Pragma("unroll")                                                                \
    for (int m_ = 0; m_ < 4; ++m_) af_[m_] = *(const s16x8*)&a_l[buf][m_ * 16 + r16][khalf]; \
    _Pragma("unroll")                                                                \
    for (int n_ = 0; n_ < 4; ++n_) bf_[n_] = *(const s16x8*)&b_l[buf][wc + n_ * 16 + r16][khalf]; \
    _Pragma("unroll")                                                                \
    for (int m_ = 0; m_ < 4; ++m_)                                                   \
        _Pragma("unroll")                                                            \
        for (int n_ = 0; n_ < 4; ++n_)                                               \
            acc[m_][n_] = __builtin_amdgcn_mfma_f32_16x16x32_bf16(af_[m_], bf_[n_], acc[m_][n_], 0, 0, 0); \
} while (0)

    LOAD_TILE(0, 0);
    LOAD_TILE(1, 1);
    STORE_TILE(0, 0);
    __syncthreads();

    for (int i = 0; i < nt; i += 2){
        LOAD_TILE(0, (i + 2 < nt ? i + 2 : nt - 1));
        COMPUTE(0);
        STORE_TILE(1, 1);
        __syncthreads();
        LOAD_TILE(1, (i + 3 < nt ? i + 3 : nt - 1));
        COMPUTE(1);
        STORE_TILE(0, 0);
        __syncthreads();
    }

#undef LOAD_TILE
#undef STORE_TILE
#undef COMPUTE

    int r4 = (lane >> 4) * 4, c16 = lane & 15;
    #pragma unroll
    for (int m = 0; m < 4; ++m)
        #pragma unroll
        for (int n = 0; n < 4; ++n)
            #pragma unroll
            for (int r = 0; r < 4; ++r){
                int gr = grow0 + m * 16 + r4 + r;
                int gc = wc + n * 16 + c16;
                float v = acc[m][n][r];
                if (EPI == 0)      v *= rowscale[gr];
                else if (EPI == 1) v += bias[gc];
                else {
                    v = fmaxf(rowscale[gr] * (v + bf2f(aux[(size_t)gr * 512 + gc])) + bias[gc], 0.f);
                }
                Out[(size_t)gr * 512 + gc] = f2bf(v);
            }
}

// ---------------- sel = softmax(t1 @ Wm2 + bm2), one wave per node ----------------
__global__ void sel_kernel(const u16* __restrict__ t1, const float* __restrict__ Wm2,
                           const float* __restrict__ bm2, float* __restrict__ sel){
    int n = blockIdx.x * 4 + (threadIdx.x >> 6);
    int lane = threadIdx.x & 63;
    u32x4 v = *(const u32x4*)(t1 + (size_t)n * 512 + lane * 8);
    float tv[8];
    tv[0]=bf2f((u16)(v.x&0xffff)); tv[1]=bf2f((u16)(v.x>>16));
    tv[2]=bf2f((u16)(v.y&0xffff)); tv[3]=bf2f((u16)(v.y>>16));
    tv[4]=bf2f((u16)(v.z&0xffff)); tv[5]=bf2f((u16)(v.z>>16));
    tv[6]=bf2f((u16)(v.w&0xffff)); tv[7]=bf2f((u16)(v.w>>16));
    float acc[CCL];
    #pragma unroll
    for (int c = 0; c < CCL; ++c) acc[c] = 0.f;
    #pragma unroll
    for (int i = 0; i < 8; ++i){
        const float* wr = Wm2 + (size_t)(lane * 8 + i) * CCL;
        #pragma unroll
        for (int c = 0; c < CCL; ++c) acc[c] += tv[i] * wr[c];
    }
    #pragma unroll
    for (int m = 1; m < 64; m <<= 1)
        #pragma unroll
        for (int c = 0; c < CCL; ++c) acc[c] += __shfl_xor(acc[c], m);
    if (lane == 0){
        float mx = -1e30f;
        #pragma unroll
        for (int c = 0; c < CCL; ++c){ acc[c] += bm2[c]; mx = fmaxf(mx, acc[c]); }
        float s = 0.f;
        #pragma unroll
        for (int c = 0; c < CCL; ++c){ acc[c] = expf(acc[c] - mx); s += acc[c]; }
        float inv = 1.f / s;
        #pragma unroll
        for (int c = 0; c < CCL; ++c) sel[(size_t)n * CCL + c] = acc[c] * inv;
    }
}

__device__ __forceinline__ float selu(float x){
    const float sc = 1.0507009873554804934193349852946f;
    const float al = 1.6732632423543772848170429916717f;
    return x > 0.f ? sc * x : sc * al * (expf(x) - 1.f);
}

// ---------------- out[b][c][h] = selu(sum_n sel[n][c]*h1[n][h]) ----------------
__global__ void out_kernel(const float* __restrict__ sel, const u16* __restrict__ h1,
                           float* __restrict__ outp){
    int b = blockIdx.x >> 2, hb = blockIdx.x & 3;
    int t = threadIdx.x;   // 128
    __shared__ float sel_l[PG * CCL];
    for (int i = t; i < PG * CCL; i += 128) sel_l[i] = sel[(size_t)b * PG * CCL + i];
    __syncthreads();
    int h = hb * 128 + t;
    float acc[CCL];
    #pragma unroll
    for (int c = 0; c < CCL; ++c) acc[c] = 0.f;
    const u16* hp = h1 + (size_t)b * PG * 512 + h;
    for (int n = 0; n < PG; ++n){
        float v = bf2f(hp[(size_t)n * 512]);
        const float* s = sel_l + n * CCL;
        #pragma unroll
        for (int c = 0; c < CCL; ++c) acc[c] += v * s[c];
    }
    #pragma unroll
    for (int c = 0; c < CCL; ++c)
        outp[((size_t)b * CCL + c) * 512 + h] = selu(acc[c]);
}

// ---------------- per-graph pooling losses + normalized coarse adjacency ----------------
__global__ void pool_kernel(const float* __restrict__ sel, const float* __restrict__ adj,
                            const float* __restrict__ degs, float* __restrict__ oan,
                            float* __restrict__ scal){
    int b = blockIdx.x, t = threadIdx.x;   // 256
    __shared__ float sel_l[PG * CCL];
    __shared__ float u_l[PG * CCL];
    __shared__ float deg_l[PG];
    __shared__ float ss_l[144], oa_l[144];
    __shared__ float ca_l[CCL], cs_l[CCL], rs_l[CCL];
    __shared__ float msum;
    for (int i = t; i < PG * CCL; i += 256) sel_l[i] = sel[(size_t)b * PG * CCL + i];
    deg_l[t] = degs[b * PG + t];
    __syncthreads();
    {
        float u[CCL];
        #pragma unroll
        for (int c = 0; c < CCL; ++c) u[c] = 0.f;
        const float* adjb = adj + (size_t)b * PG * PG;
        for (int j = 0; j < PG; ++j){
            float a = adjb[j * PG + t];
            const float* s = sel_l + j * CCL;
            #pragma unroll
            for (int c = 0; c < CCL; ++c) u[c] += a * s[c];
        }
        #pragma unroll
        for (int c = 0; c < CCL; ++c) u_l[t * CCL + c] = u[c];
    }
    __syncthreads();
    if (t < 144){
        int c = t / 12, k = t % 12;
        float ssv = 0.f, oav = 0.f;
        for (int n = 0; n < PG; ++n){
            ssv += sel_l[n * CCL + c] * sel_l[n * CCL + k];
            oav += sel_l[n * CCL + c] * u_l[n * CCL + k];
        }
        ss_l[t] = ssv; oa_l[t] = oav;
    } else if (t < 156){
        int c = t - 144; float cs = 0.f, ca = 0.f;
        for (int n = 0; n < PG; ++n){
            float s = sel_l[n * CCL + c];
            cs += s; ca += s * deg_l[n];
        }
        cs_l[c] = cs; ca_l[c] = ca;
    } else if (t == 156){
        float s = 0.f;
        for (int n = 0; n < PG; ++n) s += deg_l[n];
        msum = s;
    }
    __syncthreads();
    if (t == 0){
        float m = msum * 0.5f;
        float inv2m = 1.f / (2.f * m);
        float sp = 0.f;
        for (int c = 0; c < CCL; ++c) sp += oa_l[c * 13] - ca_l[c] * ca_l[c] * inv2m;
        scal[b] = -sp * inv2m;
        float s2 = 0.f;
        for (int i = 0; i < 144; ++i) s2 += ss_l[i] * ss_l[i];
        float ssn = sqrtf(s2);
        const float isq = 0.28867513459481288f;
        float o2 = 0.f;
        for (int i = 0; i < 144; ++i){
            float d = ss_l[i] / ssn - ((i % 13 == 0) ? isq : 0.f);
            o2 += d * d;
        }
        scal[64 + b] = sqrtf(o2);
        float c2 = 0.f;
        for (int c = 0; c < CCL; ++c) c2 += cs_l[c] * cs_l[c];
        scal[128 + b] = sqrtf(c2) * (sqrtf(12.f) / 256.f) - 1.f;
    }
    if (t < CCL){
        float r = 0.f;
        for (int k = 0; k < CCL; ++k) if (k != t) r += oa_l[t * CCL + k];
        rs_l[t] = sqrtf(r) + 1e-15f;
    }
    __syncthreads();
    if (t < 144){
        int c = t / 12, k = t % 12;
        float v = (c == k) ? 0.f : oa_l[t] / (rs_l[c] * rs_l[k]);
        oan[(size_t)b * 144 + t] = v;
    }
}

// ---------------- head: g = mean_c(h2), MLP, logits ----------------
__global__ void head_kernel(const float* __restrict__ outp, const float* __restrict__ oan,
                            const float* __restrict__ Wrel, const float* __restrict__ brel,
                            const float* __restrict__ Wroot,
                            const float* __restrict__ Wl1, const float* __restrict__ bl1,
                            const float* __restrict__ Wl2, const float* __restrict__ bl2,
                            float* __restrict__ dout){
    int b = blockIdx.x, t = threadIdx.x;  // 256
    __shared__ float out_l[CCL * 512];
    __shared__ float w12[CCL];
    __shared__ float v1l[512], v2l[512], gprel[512], gl[512];
    for (int i = t; i < CCL * 512; i += 256) out_l[i] = outp[(size_t)b * CCL * 512 + i];
    if (t < CCL){
        float s = 0.f;
        for (int c = 0; c < CCL; ++c) s += oan[(size_t)b * 144 + c * CCL + t];
        w12[t] = s * (1.f / 12.f);
    }
    __syncthreads();
    for (int h = t; h < 512; h += 256){
        float a1 = 0.f, a2 = 0.f;
        #pragma unroll
        for (int k = 0; k < CCL; ++k){ a1 += w12[k] * out_l[k * 512 + h]; a2 += out_l[k * 512 + h]; }
        v1l[h] = a1; v2l[h] = a2 * (1.f / 12.f);
    }
    __syncthreads();
    for (int h = t; h < 512; h += 256){
        float acc = brel[h];
        for (int k = 0; k < 512; ++k)
            acc += v1l[k] * Wrel[(size_t)k * 512 + h] + v2l[k] * Wroot[(size_t)k * 512 + h];
        gprel[h] = acc;
    }
    __syncthreads();
    for (int h = t; h < 512; h += 256){
        float acc = bl1[h];
        for (int k = 0; k < 512; ++k) acc += gprel[k] * Wl1[(size_t)k * 512 + h];
        gl[h] = fmaxf(acc, 0.f);
    }
    __syncthreads();
    if (t < 64){
        float acc[5] = {0.f, 0.f, 0.f, 0.f, 0.f};
        for (int h = t; h < 512; h += 64){
            float g = gl[h];
            #pragma unroll
            for (int o = 0; o < 5; ++o) acc[o] += g * Wl2[(size_t)h * 5 + o];
        }
        #pragma unroll
        for (int m = 1; m < 64; m <<= 1)
            #pragma unroll
            for (int o = 0; o < 5; ++o) acc[o] += __shfl_xor(acc[o], m);
        if (t == 0){
            #pragma unroll
            for (int o = 0; o < 5; ++o) dout[b * 5 + o] = acc[o] + bl2[o];
        }
    }
}

__global__ void loss_kernel(const float* __restrict__ scal, float* __restrict__ dout){
    int t = threadIdx.x;  // 64
    float v = scal[t] + scal[64 + t] + scal[128 + t];
    #pragma unroll
    for (int m = 1; m < 64; m <<= 1) v += __shfl_xor(v, m);
    if (t == 0) dout[BGR * 5] = v * (1.f / 64.f);
}

extern "C" void kernel_launch(void* const* d_in, const int* in_sizes, int n_in,
                              void* d_out, int out_size, void* d_ws, size_t ws_size,
                              hipStream_t stream)
{
    const float* x    = (const float*)d_in[0];
    const int*   ei   = (const int*)d_in[1];
    const float* W1   = (const float*)d_in[3];
    const float* b1   = (const float*)d_in[4];
    const float* Wm1  = (const float*)d_in[5];
    const float* bm1  = (const float*)d_in[6];
    const float* Wm2  = (const float*)d_in[7];
    const float* bm2  = (const float*)d_in[8];
    const float* Wrel = (const float*)d_in[9];
    const float* brel = (const float*)d_in[10];
    const float* Wroot= (const float*)d_in[11];
    const float* Wl1  = (const float*)d_in[12];
    const float* bl1  = (const float*)d_in[13];
    const float* Wl2  = (const float*)d_in[14];
    const float* bl2  = (const float*)d_in[15];
    float* dout = (float*)d_out;
    const int E = in_sizes[1] / 2;

    char* w = (char*)d_ws;
    float* adj  = (float*)(w + 0);            // 16 MiB
    float* degs = (float*)(w + 16777216);
    float* dinv = (float*)(w + 16842752);
    u16*   Wt   = (u16*)  (w + 16908288);     // 4 MiB (dead after GEMM1; reused below)
    u16*   Wm1t = (u16*)  (w + 21102592);     // 512 KiB
    u16*   hs   = (u16*)  (w + 21626880);     // 16 MiB (reused as t1 after agg)
    u16*   h1   = (u16*)  (w + 38404096);     // 16 MiB
    u16*   hsT  = (u16*)  (w + 55181312);     // 16 MiB
    // Wt region reuse after GEMM1/GEMM2:
    float* sel  = (float*)(w + 16908288);
    float* outp = (float*)(w + 17694720);
    float* oan  = (float*)(w + 19267584);
    float* scal = (float*)(w + 19304448);
    u16* t1 = hs;

    hipMemsetAsync(adj, 0, 16777216, stream);

    hipLaunchKernelGGL(transpose_bf16, dim3(INDIM / 32, HDIM / 32), dim3(32, 8), 0, stream,
                       W1, Wt, INDIM, HDIM);
    hipLaunchKernelGGL(transpose_bf16, dim3(HDIM / 32, HDIM / 32), dim3(32, 8), 0, stream,
                       Wm1, Wm1t, HDIM, HDIM);
    hipLaunchKernelGGL(build_adj, dim3((E + 255) / 256), dim3(256), 0, stream, ei, adj, E);
    hipLaunchKernelGGL(rowsum_deg, dim3(NODES / 4), dim3(256), 0, stream, adj, degs, dinv);

    // GEMM1: hs = bf16(dinv_r * (x @ W1))   [16384,512], A read once
    hipLaunchKernelGGL((gemm512<1, 0>), dim3(NODES / 64, 1), dim3(512), 0, stream,
                       (const void*)x, INDIM, 0, Wt, INDIM, 0, hs,
                       dinv, (const float*)nullptr, (const u16*)nullptr, INDIM, 0);

    // hsT[h][node] for agg B^T
    hipLaunchKernelGGL(transpose_u16, dim3(NODES / 32, HDIM / 32), dim3(32, 8), 0, stream,
                       hs, hsT, NODES, HDIM);

    // dense GCN agg (batched per graph): h1 = relu(dinv_r*(A_g@hs_g + hs_r) + b1)
    hipLaunchKernelGGL((gemm512<1, 2>), dim3(PG / 64, BGR), dim3(512), 0, stream,
                       (const void*)adj, PG, PG * PG, hsT, NODES, PG, h1,
                       dinv, b1, hs, PG, PG);

    // GEMM2: t1 = bf16(h1 @ Wm1 + bm1)
    hipLaunchKernelGGL((gemm512<0, 1>), dim3(NODES / 64, 1), dim3(512), 0, stream,
                       (const void*)h1, HDIM, 0, Wm1t, HDIM, 0, t1,
                       (const float*)nullptr, bm1, (const u16*)nullptr, HDIM, 0);

    hipLaunchKernelGGL(sel_kernel, dim3(NODES / 4), dim3(256), 0, stream, t1, Wm2, bm2, sel);
    hipLaunchKernelGGL(out_kernel, dim3(BGR * 4), dim3(128), 0, stream, sel, h1, outp);
    hipLaunchKernelGGL(pool_kernel, dim3(BGR), dim3(256), 0, stream, sel, adj, degs, oan, scal);
    hipLaunchKernelGGL(head_kernel, dim3(BGR), dim3(256), 0, stream, outp, oan,
                       Wrel, brel, Wroot, Wl1, bl1, Wl2, bl2, dout);
    hipLaunchKernelGGL(loss_kernel, dim3(1), dim3(64), 0, stream, scal, dout);
}

// Round 4
// 839.774 us; speedup vs baseline: 1.2615x; 1.0315x over previous
//
#include <hip/hip_runtime.h>
#include <stdint.h>

typedef unsigned short u16;
typedef unsigned int   u32;
typedef float  f32x2 __attribute__((ext_vector_type(2)));
typedef float  f32x4 __attribute__((ext_vector_type(4)));
typedef u32    u32x2 __attribute__((ext_vector_type(2)));
typedef u32    u32x4 __attribute__((ext_vector_type(4)));
typedef short  s16x8 __attribute__((ext_vector_type(8)));

#define NODES 16384
#define BGR   64
#define PG    256
#define HDIM  512
#define INDIM 4096
#define CCL   12

__device__ __forceinline__ float bf2f(u16 u){ u32 x = ((u32)u) << 16; return __uint_as_float(x); }
__device__ __forceinline__ u16 f2bf(float f){
    u32 x = __float_as_uint(f);
    return (u16)((x + 0x7fffu + ((x >> 16) & 1u)) >> 16);
}
__device__ __forceinline__ u32 pk2(float a, float b){ return (u32)f2bf(a) | ((u32)f2bf(b) << 16); }

// ---------------- transpose + fp32->bf16:  Wt[n][k] = bf16(W[k][n]) ----------------
__global__ void transpose_bf16(const float* __restrict__ W, u16* __restrict__ Wt, int K, int N){
    __shared__ float tile[32][33];
    int k0 = blockIdx.x * 32, n0 = blockIdx.y * 32;
    int tx = threadIdx.x, ty = threadIdx.y;      // (32,8)
    #pragma unroll
    for (int j = 0; j < 4; ++j)
        tile[ty + 8*j][tx] = W[(size_t)(k0 + ty + 8*j) * N + n0 + tx];
    __syncthreads();
    #pragma unroll
    for (int j = 0; j < 4; ++j)
        Wt[(size_t)(n0 + ty + 8*j) * K + k0 + tx] = f2bf(tile[tx][ty + 8*j]);
}

// ---------------- u16 transpose: out[c][r] = in[r][c] ----------------
__global__ void transpose_u16(const u16* __restrict__ in, u16* __restrict__ out, int R, int C){
    __shared__ u16 tile[32][33];
    int r0 = blockIdx.x * 32, c0 = blockIdx.y * 32;
    int tx = threadIdx.x, ty = threadIdx.y;      // (32,8)
    #pragma unroll
    for (int j = 0; j < 4; ++j)
        tile[ty + 8*j][tx] = in[(size_t)(r0 + ty + 8*j) * C + c0 + tx];
    __syncthreads();
    #pragma unroll
    for (int j = 0; j < 4; ++j)
        out[(size_t)(c0 + ty + 8*j) * R + r0 + tx] = tile[tx][ty + 8*j];
}

// ---------------- build dense per-graph adjacency (counts) ----------------
__global__ void build_adj(const int* __restrict__ ei, float* __restrict__ adj, int E){
    int e = blockIdx.x * 256 + threadIdx.x;
    if (e < E){
        int s = ei[e];
        int d = ei[E + e];
        atomicAdd(&adj[(size_t)s * 256 + (d & 255)], 1.0f);
    }
}

// ---------------- row sums -> degrees (DMoN) and dinv (GCN, +1 self loop) ----------------
__global__ void rowsum_deg(const float* __restrict__ adj, float* __restrict__ degs,
                           float* __restrict__ dinv){
    int r = blockIdx.x * 4 + (threadIdx.x >> 6);
    int lane = threadIdx.x & 63;
    const float* row = adj + (size_t)r * 256;
    float s = row[lane] + row[lane + 64] + row[lane + 128] + row[lane + 192];
    #pragma unroll
    for (int m = 1; m < 64; m <<= 1) s += __shfl_xor(s, m);
    if (lane == 0){ degs[r] = s; dinv[r] = 1.0f / sqrtf(s + 1.0f); }
}

// ---------------- unified bf16 MFMA GEMM: 64(M) x (NT*64)(N) tile, BK=32, dbuf LDS ----
// AF32: A fp32 (convert in staging). EPI: 0 = rowscale*acc; 1 = acc+bias[c];
//   2 = relu(rowscale[r]*(acc+aux[r][c])+bias[c]); 3 = raw partial (split-K)
// NT: waves per block = BN/64. SK: split-K factor.
template<int AF32, int EPI, int NT, int SK>
__global__ __launch_bounds__(NT*64, NT == 8 ? 4 : 3) void gemm512(
    const void* __restrict__ Ap, int lda, long abstride,
    const u16* __restrict__ Bt, int ldb, long btstride,
    u16* __restrict__ Out, size_t osplit,
    const float* __restrict__ rowscale, const float* __restrict__ bias,
    const u16* __restrict__ aux, int K, int prows, int nbn)
{
    constexpr int BN  = NT * 64;
    constexpr int AEL = 2048 / BN;              // A elems per thread (4 or 8)
    int bx = blockIdx.x;
    int s    = bx % SK;  bx /= SK;
    int nblk = bx % nbn;
    int m0l  = (bx / nbn) * 64;
    int n0   = nblk * BN;
    int g    = blockIdx.y;
    int t = threadIdx.x, lane = t & 63, w = t >> 6;
    int wc = w * 64;
    int grow0 = g * prows + m0l;

    __shared__ __align__(16) u16 a_l[2][64][36];
    __shared__ __align__(16) u16 b_l[2][BN][34];

    f32x4 acc[4][4];
    #pragma unroll
    for (int m = 0; m < 4; ++m)
        #pragma unroll
        for (int n = 0; n < 4; ++n) acc[m][n] = (f32x4)0.0f;

    const float* A32 = (const float*)Ap + (size_t)g * abstride;
    const u16*   A16 = (const u16*)Ap + (size_t)g * abstride;
    const u16*   Bp  = Bt + (size_t)g * btstride;

    int arow, acol;
    if (NT == 8){ arow = t >> 3; acol = (t & 7) * 4; }
    else        { arow = t >> 2; acol = (t & 3) * 8; }
    int r16 = lane & 15, khalf = (lane >> 4) * 8;
    const int kbase = s * (K / SK);
    const int nt = (K / SK) / 32;

    f32x4 raF[2][AEL / 4];
    u32   raH[2][AEL / 2];
    u32x4 rb[2][4];

#define LOAD_TILE(S, kt) do {                                                         \
    int k0_ = kbase + (kt) * 32;                                                      \
    if (AF32){                                                                        \
        _Pragma("unroll")                                                             \
        for (int q_ = 0; q_ < AEL / 4; ++q_)                                          \
            raF[S][q_] = *(const f32x4*)(A32 + (size_t)(m0l + arow) * lda + k0_ + acol + q_ * 4); \
    } else {                                                                          \
        if (AEL == 4) *(u32x2*)&raH[S][0] = *(const u32x2*)(A16 + (size_t)(m0l + arow) * lda + k0_ + acol); \
        else          *(u32x4*)&raH[S][0] = *(const u32x4*)(A16 + (size_t)(m0l + arow) * lda + k0_ + acol); \
    }                                                                                 \
    const u16* bp_ = Bp + (size_t)(n0 + t) * ldb + k0_;                               \
    _Pragma("unroll")                                                                 \
    for (int j_ = 0; j_ < 4; ++j_) rb[S][j_] = *(const u32x4*)(bp_ + j_ * 8);         \
} while (0)

#define STORE_TILE(S, buf) do {                                                       \
    if (AF32){                                                                        \
        _Pragma("unroll")                                                             \
        for (int q_ = 0; q_ < AEL / 4; ++q_){                                         \
            u32x2 aw_ = { pk2(raF[S][q_].x, raF[S][q_].y), pk2(raF[S][q_].z, raF[S][q_].w) }; \
            *(u32x2*)&a_l[buf][arow][acol + q_ * 4] = aw_;                            \
        }                                                                             \
    } else {                                                                          \
        if (AEL == 4) *(u32x2*)&a_l[buf][arow][acol] = *(u32x2*)&raH[S][0];           \
        else          *(u32x4*)&a_l[buf][arow][acol] = *(u32x4*)&raH[S][0];           \
    }                                                                                 \
    _Pragma("unroll")                                                                 \
    for (int j_ = 0; j_ < 4; ++j_) *(u32x4*)&b_l[buf][t][j_ * 8] = rb[S][j_];         \
} while (0)

#define COMPUTE(buf) do {                                                             \
    s16x8 af_[4], bf_[4];                                                             \
    _Pragma("unroll")                                                                 \
    for (int m_ = 0; m_ < 4; ++m_) af_[m_] = *(const s16x8*)&a_l[buf][m_ * 16 + r16][khalf]; \
    _Pragma("unroll")                                                                 \
    for (int n_ = 0; n_ < 4; ++n_) bf_[n_] = *(const s16x8*)&b_l[buf][wc + n_ * 16 + r16][khalf]; \
    _Pragma("unroll")                                                                 \
    for (int m_ = 0; m_ < 4; ++m_)                                                    \
        _Pragma("unroll")                                                             \
        for (int n_ = 0; n_ < 4; ++n_)                                                \
            acc[m_][n_] = __builtin_amdgcn_mfma_f32_16x16x32_bf16(af_[m_], bf_[n_], acc[m_][n_], 0, 0, 0); \
} while (0)

    LOAD_TILE(0, 0);
    LOAD_TILE(1, 1);
    STORE_TILE(0, 0);
    __syncthreads();

    for (int i = 0; i < nt; i += 2){
        LOAD_TILE(0, (i + 2 < nt ? i + 2 : nt - 1));
        COMPUTE(0);
        STORE_TILE(1, 1);
        __syncthreads();
        LOAD_TILE(1, (i + 3 < nt ? i + 3 : nt - 1));
        COMPUTE(1);
        STORE_TILE(0, 0);
        __syncthreads();
    }

#undef LOAD_TILE
#undef STORE_TILE
#undef COMPUTE

    u16* Op = Out + (size_t)s * osplit;
    int r4 = (lane >> 4) * 4, c16 = lane & 15;
    #pragma unroll
    for (int m = 0; m < 4; ++m)
        #pragma unroll
        for (int n = 0; n < 4; ++n)
            #pragma unroll
            for (int r = 0; r < 4; ++r){
                int gr = grow0 + m * 16 + r4 + r;
                int gc = n0 + wc + n * 16 + c16;
                float v = acc[m][n][r];
                if (EPI == 0)      v *= rowscale[gr];
                else if (EPI == 1) v += bias[gc];
                else if (EPI == 2)
                    v = fmaxf(rowscale[gr] * (v + bf2f(aux[(size_t)gr * 512 + gc])) + bias[gc], 0.f);
                Op[(size_t)gr * 512 + gc] = f2bf(v);
            }
}

// ---------------- combine split-K partials: hs = bf16(dinv_r*(p0+p1)) ----------------
__global__ void combine_k(const u16* __restrict__ p, const float* __restrict__ dinv,
                          u16* __restrict__ hs){
    size_t i = (size_t)blockIdx.x * 256 + threadIdx.x;
    u32x4 a = *(const u32x4*)(p + i * 8);
    u32x4 b = *(const u32x4*)(p + (size_t)NODES * 512 + i * 8);
    float d = dinv[i >> 6];
    u32x4 o;
    o.x = pk2(d * (bf2f((u16)(a.x & 0xffff)) + bf2f((u16)(b.x & 0xffff))),
              d * (bf2f((u16)(a.x >> 16))    + bf2f((u16)(b.x >> 16))));
    o.y = pk2(d * (bf2f((u16)(a.y & 0xffff)) + bf2f((u16)(b.y & 0xffff))),
              d * (bf2f((u16)(a.y >> 16))    + bf2f((u16)(b.y >> 16))));
    o.z = pk2(d * (bf2f((u16)(a.z & 0xffff)) + bf2f((u16)(b.z & 0xffff))),
              d * (bf2f((u16)(a.z >> 16))    + bf2f((u16)(b.z >> 16))));
    o.w = pk2(d * (bf2f((u16)(a.w & 0xffff)) + bf2f((u16)(b.w & 0xffff))),
              d * (bf2f((u16)(a.w >> 16))    + bf2f((u16)(b.w >> 16))));
    *(u32x4*)(hs + i * 8) = o;
}

// ---------------- sel = softmax(t1 @ Wm2 + bm2), one wave per node ----------------
__global__ void sel_kernel(const u16* __restrict__ t1, const float* __restrict__ Wm2,
                           const float* __restrict__ bm2, float* __restrict__ sel){
    int n = blockIdx.x * 4 + (threadIdx.x >> 6);
    int lane = threadIdx.x & 63;
    u32x4 v = *(const u32x4*)(t1 + (size_t)n * 512 + lane * 8);
    float tv[8];
    tv[0]=bf2f((u16)(v.x&0xffff)); tv[1]=bf2f((u16)(v.x>>16));
    tv[2]=bf2f((u16)(v.y&0xffff)); tv[3]=bf2f((u16)(v.y>>16));
    tv[4]=bf2f((u16)(v.z&0xffff)); tv[5]=bf2f((u16)(v.z>>16));
    tv[6]=bf2f((u16)(v.w&0xffff)); tv[7]=bf2f((u16)(v.w>>16));
    float acc[CCL];
    #pragma unroll
    for (int c = 0; c < CCL; ++c) acc[c] = 0.f;
    #pragma unroll
    for (int i = 0; i < 8; ++i){
        const float* wr = Wm2 + (size_t)(lane * 8 + i) * CCL;
        #pragma unroll
        for (int c = 0; c < CCL; ++c) acc[c] += tv[i] * wr[c];
    }
    #pragma unroll
    for (int m = 1; m < 64; m <<= 1)
        #pragma unroll
        for (int c = 0; c < CCL; ++c) acc[c] += __shfl_xor(acc[c], m);
    if (lane == 0){
        float mx = -1e30f;
        #pragma unroll
        for (int c = 0; c < CCL; ++c){ acc[c] += bm2[c]; mx = fmaxf(mx, acc[c]); }
        float s = 0.f;
        #pragma unroll
        for (int c = 0; c < CCL; ++c){ acc[c] = expf(acc[c] - mx); s += acc[c]; }
        float inv = 1.f / s;
        #pragma unroll
        for (int c = 0; c < CCL; ++c) sel[(size_t)n * CCL + c] = acc[c] * inv;
    }
}

__device__ __forceinline__ float selu(float x){
    const float sc = 1.0507009873554804934193349852946f;
    const float al = 1.6732632423543772848170429916717f;
    return x > 0.f ? sc * x : sc * al * (expf(x) - 1.f);
}

// ---------------- out[b][c][h] = selu(sum_n sel[n][c]*h1[n][h]) ----------------
__global__ void out_kernel(const float* __restrict__ sel, const u16* __restrict__ h1,
                           float* __restrict__ outp){
    int b = blockIdx.x >> 1, hb = blockIdx.x & 1;
    int t = threadIdx.x;   // 128
    __shared__ float sel_l[PG * CCL];
    for (int i = t; i < PG * CCL; i += 128) sel_l[i] = sel[(size_t)b * PG * CCL + i];
    __syncthreads();
    int h0 = hb * 256 + t * 2;
    float acc0[CCL], acc1[CCL];
    #pragma unroll
    for (int c = 0; c < CCL; ++c){ acc0[c] = 0.f; acc1[c] = 0.f; }
    const u16* hp = h1 + (size_t)b * PG * 512 + h0;
    for (int n = 0; n < PG; ++n){
        u32 hv = *(const u32*)(hp + (size_t)n * 512);
        float v0 = bf2f((u16)(hv & 0xffff)), v1 = bf2f((u16)(hv >> 16));
        const float* s = sel_l + n * CCL;
        #pragma unroll
        for (int c = 0; c < CCL; ++c){ acc0[c] += v0 * s[c]; acc1[c] += v1 * s[c]; }
    }
    #pragma unroll
    for (int c = 0; c < CCL; ++c){
        f32x2 ov = { selu(acc0[c]), selu(acc1[c]) };
        *(f32x2*)&outp[((size_t)b * CCL + c) * 512 + h0] = ov;
    }
}

// ---------------- per-graph pooling losses + normalized coarse adjacency ----------------
__global__ void pool_kernel(const float* __restrict__ sel, const float* __restrict__ adj,
                            const float* __restrict__ degs, float* __restrict__ oan,
                            float* __restrict__ scal){
    int b = blockIdx.x, t = threadIdx.x;   // 256
    __shared__ float sel_l[PG * CCL];
    __shared__ float u_l[PG * CCL];
    __shared__ float deg_l[PG];
    __shared__ float ss_l[144], oa_l[144];
    __shared__ float ca_l[CCL], cs_l[CCL], rs_l[CCL];
    __shared__ float msum;
    for (int i = t; i < PG * CCL; i += 256) sel_l[i] = sel[(size_t)b * PG * CCL + i];
    deg_l[t] = degs[b * PG + t];
    __syncthreads();
    {
        float u[CCL];
        #pragma unroll
        for (int c = 0; c < CCL; ++c) u[c] = 0.f;
        const float* adjb = adj + (size_t)b * PG * PG;
        for (int j = 0; j < PG; ++j){
            float a = adjb[j * PG + t];
            const float* s = sel_l + j * CCL;
            #pragma unroll
            for (int c = 0; c < CCL; ++c) u[c] += a * s[c];
        }
        #pragma unroll
        for (int c = 0; c < CCL; ++c) u_l[t * CCL + c] = u[c];
    }
    __syncthreads();
    if (t < 144){
        int c = t / 12, k = t % 12;
        float ssv = 0.f, oav = 0.f;
        for (int n = 0; n < PG; ++n){
            ssv += sel_l[n * CCL + c] * sel_l[n * CCL + k];
            oav += sel_l[n * CCL + c] * u_l[n * CCL + k];
        }
        ss_l[t] = ssv; oa_l[t] = oav;
    } else if (t < 156){
        int c = t - 144; float cs = 0.f, ca = 0.f;
        for (int n = 0; n < PG; ++n){
            float s = sel_l[n * CCL + c];
            cs += s; ca += s * deg_l[n];
        }
        cs_l[c] = cs; ca_l[c] = ca;
    } else if (t == 156){
        float s = 0.f;
        for (int n = 0; n < PG; ++n) s += deg_l[n];
        msum = s;
    }
    __syncthreads();
    if (t == 0){
        float m = msum * 0.5f;
        float inv2m = 1.f / (2.f * m);
        float sp = 0.f;
        for (int c = 0; c < CCL; ++c) sp += oa_l[c * 13] - ca_l[c] * ca_l[c] * inv2m;
        scal[b] = -sp * inv2m;
        float s2 = 0.f;
        for (int i = 0; i < 144; ++i) s2 += ss_l[i] * ss_l[i];
        float ssn = sqrtf(s2);
        const float isq = 0.28867513459481288f;
        float o2 = 0.f;
        for (int i = 0; i < 144; ++i){
            float d = ss_l[i] / ssn - ((i % 13 == 0) ? isq : 0.f);
            o2 += d * d;
        }
        scal[64 + b] = sqrtf(o2);
        float c2 = 0.f;
        for (int c = 0; c < CCL; ++c) c2 += cs_l[c] * cs_l[c];
        scal[128 + b] = sqrtf(c2) * (sqrtf(12.f) / 256.f) - 1.f;
    }
    if (t < CCL){
        float r = 0.f;
        for (int k = 0; k < CCL; ++k) if (k != t) r += oa_l[t * CCL + k];
        rs_l[t] = sqrtf(r) + 1e-15f;
    }
    __syncthreads();
    if (t < 144){
        int c = t / 12, k = t % 12;
        float v = (c == k) ? 0.f : oa_l[t] / (rs_l[c] * rs_l[k]);
        oan[(size_t)b * 144 + t] = v;
    }
}

// ---------------- pool2: v1T[h][g], v2T[h][g] ----------------
__global__ void pool2_kernel(const float* __restrict__ outp, const float* __restrict__ oan,
                             float* __restrict__ v1T, float* __restrict__ v2T){
    int b = blockIdx.x, t = threadIdx.x;  // 256
    __shared__ float out_l[CCL * 512];
    __shared__ float w12[CCL];
    for (int i = t; i < CCL * 512; i += 256) out_l[i] = outp[(size_t)b * CCL * 512 + i];
    if (t < CCL){
        float s = 0.f;
        for (int c = 0; c < CCL; ++c) s += oan[(size_t)b * 144 + c * CCL + t];
        w12[t] = s * (1.f / 12.f);
    }
    __syncthreads();
    #pragma unroll
    for (int q = 0; q < 2; ++q){
        int h = t + q * 256;
        float a1 = 0.f, a2 = 0.f;
        #pragma unroll
        for (int k = 0; k < CCL; ++k){
            float o = out_l[k * 512 + h];
            a1 += w12[k] * o; a2 += o;
        }
        v1T[(size_t)h * 64 + b] = a1;
        v2T[(size_t)h * 64 + b] = a2 * (1.f / 12.f);
    }
}

// ---------------- weight-stationary dense layer over all graphs ----------------
// OT[c][g] = (relu?)( sum_k V1T[k][g]*W1[k][c] (+ V2T[k][g]*W2[k][c]) + bias[c] )
template<int TWO, int RELU>
__global__ void head_ab(const float* __restrict__ V1T, const float* __restrict__ W1,
                        const float* __restrict__ V2T, const float* __restrict__ W2,
                        const float* __restrict__ bias, float* __restrict__ OT){
    int c0 = blockIdx.x * 2;
    int t = threadIdx.x;           // 256
    int g = t & 63, hc = (t >> 6) & 1, ks = t >> 7;
    __shared__ float red[2][2][64];
    float acc = 0.f;
    int kend = ks * 256 + 256;
    for (int k = ks * 256; k < kend; ++k){
        acc += V1T[(size_t)k * 64 + g] * W1[(size_t)k * 512 + c0 + hc];
        if (TWO) acc += V2T[(size_t)k * 64 + g] * W2[(size_t)k * 512 + c0 + hc];
    }
    red[hc][ks][g] = acc;
    __syncthreads();
    if (t < 128){
        int hc2 = t >> 6, g2 = t & 63;
        float v = red[hc2][0][g2] + red[hc2][1][g2] + bias[c0 + hc2];
        if (RELU) v = fmaxf(v, 0.f);
        OT[(size_t)(c0 + hc2) * 64 + g2] = v;
    }
}

// ---------------- logits: dout[g][o] = sum_k glT[k][g]*Wl2[k][o] + bl2[o] ----------------
__global__ void head_c(const float* __restrict__ glT, const float* __restrict__ Wl2,
                       const float* __restrict__ bl2, float* __restrict__ dout){
    int t = threadIdx.x;           // 320
    int o = t >> 6, g = t & 63;
    float acc = 0.f;
    for (int k = 0; k < 512; ++k)
        acc += glT[(size_t)k * 64 + g] * Wl2[(size_t)k * 5 + o];
    dout[g * 5 + o] = acc + bl2[o];
}

__global__ void loss_kernel(const float* __restrict__ scal, float* __restrict__ dout){
    int t = threadIdx.x;  // 64
    float v = scal[t] + scal[64 + t] + scal[128 + t];
    #pragma unroll
    for (int m = 1; m < 64; m <<= 1) v += __shfl_xor(v, m);
    if (t == 0) dout[BGR * 5] = v * (1.f / 64.f);
}

extern "C" void kernel_launch(void* const* d_in, const int* in_sizes, int n_in,
                              void* d_out, int out_size, void* d_ws, size_t ws_size,
                              hipStream_t stream)
{
    const float* x    = (const float*)d_in[0];
    const int*   ei   = (const int*)d_in[1];
    const float* W1   = (const float*)d_in[3];
    const float* b1   = (const float*)d_in[4];
    const float* Wm1  = (const float*)d_in[5];
    const float* bm1  = (const float*)d_in[6];
    const float* Wm2  = (const float*)d_in[7];
    const float* bm2  = (const float*)d_in[8];
    const float* Wrel = (const float*)d_in[9];
    const float* brel = (const float*)d_in[10];
    const float* Wroot= (const float*)d_in[11];
    const float* Wl1  = (const float*)d_in[12];
    const float* bl1  = (const float*)d_in[13];
    const float* Wl2  = (const float*)d_in[14];
    const float* bl2  = (const float*)d_in[15];
    float* dout = (float*)d_out;
    const int E = in_sizes[1] / 2;

    char* w = (char*)d_ws;
    float* adj  = (float*)(w + 0);            // 16 MiB
    float* degs = (float*)(w + 16777216);
    float* dinv = (float*)(w + 16842752);
    u16*   Wt   = (u16*)  (w + 16908288);     // 4 MiB (dead after GEMM1; region reused)
    u16*   Wm1t = (u16*)  (w + 21102592);     // 512 KiB
    u16*   hs   = (u16*)  (w + 21626880);     // 16 MiB (reused as t1 after agg)
    u16*   h1   = (u16*)  (w + 38404096);     // 16 MiB (p0 before agg)
    u16*   hsT  = (u16*)  (w + 55181312);     // 16 MiB (p1 before transpose)
    float* v1T  = (float*)(w + 71958528);     // 128 KiB
    float* v2T  = (float*)(w + 72089600);     // 128 KiB
    float* gpT  = (float*)(w + 72220672);     // 128 KiB
    float* glT  = (float*)(w + 72351744);     // 128 KiB
    // Wt region reuse after GEMM1:
    float* sel  = (float*)(w + 16908288);
    float* outp = (float*)(w + 17694720);
    float* oan  = (float*)(w + 19267584);
    float* scal = (float*)(w + 19304448);
    u16* t1 = hs;
    u16* parts = h1;                          // p0 = h1 region, p1 = hsT region (contiguous)

    hipMemsetAsync(adj, 0, 16777216, stream);

    hipLaunchKernelGGL(transpose_bf16, dim3(INDIM / 32, HDIM / 32), dim3(32, 8), 0, stream,
                       W1, Wt, INDIM, HDIM);
    hipLaunchKernelGGL(transpose_bf16, dim3(HDIM / 32, HDIM / 32), dim3(32, 8), 0, stream,
                       Wm1, Wm1t, HDIM, HDIM);
    hipLaunchKernelGGL(build_adj, dim3((E + 255) / 256), dim3(256), 0, stream, ei, adj, E);
    hipLaunchKernelGGL(rowsum_deg, dim3(NODES / 4), dim3(256), 0, stream, adj, degs, dinv);

    // GEMM1 split-K=2: bf16 partials into h1|hsT regions
    hipLaunchKernelGGL((gemm512<1, 3, 8, 2>), dim3((NODES / 64) * 2, 1), dim3(512), 0, stream,
                       (const void*)x, INDIM, 0L, Wt, INDIM, 0L, parts, (size_t)NODES * 512,
                       (const float*)nullptr, (const float*)nullptr, (const u16*)nullptr,
                       INDIM, 0, 1);
    hipLaunchKernelGGL(combine_k, dim3(NODES * 512 / 2048), dim3(256), 0, stream,
                       parts, dinv, hs);

    hipLaunchKernelGGL(transpose_u16, dim3(NODES / 32, HDIM / 32), dim3(32, 8), 0, stream,
                       hs, hsT, NODES, HDIM);

    // dense GCN agg (batched per graph): h1 = relu(dinv_r*(A_g@hs_g + hs_r) + b1)
    hipLaunchKernelGGL((gemm512<1, 2, 8, 1>), dim3(PG / 64, BGR), dim3(512), 0, stream,
                       (const void*)adj, PG, (long)PG * PG, hsT, NODES, (long)PG, h1, (size_t)0,
                       dinv, b1, hs, PG, PG, 1);

    // GEMM2 split-N (BN=256): t1 = bf16(h1 @ Wm1 + bm1)
    hipLaunchKernelGGL((gemm512<0, 1, 4, 1>), dim3((NODES / 64) * 2, 1), dim3(256), 0, stream,
                       (const void*)h1, HDIM, 0L, Wm1t, HDIM, 0L, t1, (size_t)0,
                       (const float*)nullptr, bm1, (const u16*)nullptr, HDIM, 0, 2);

    hipLaunchKernelGGL(sel_kernel, dim3(NODES / 4), dim3(256), 0, stream, t1, Wm2, bm2, sel);
    hipLaunchKernelGGL(out_kernel, dim3(BGR * 2), dim3(128), 0, stream, sel, h1, outp);
    hipLaunchKernelGGL(pool_kernel, dim3(BGR), dim3(256), 0, stream, sel, adj, degs, oan, scal);
    hipLaunchKernelGGL(pool2_kernel, dim3(BGR), dim3(256), 0, stream, outp, oan, v1T, v2T);
    hipLaunchKernelGGL((head_ab<1, 0>), dim3(256), dim3(256), 0, stream,
                       v1T, Wrel, v2T, Wroot, brel, gpT);
    hipLaunchKernelGGL((head_ab<0, 1>), dim3(256), dim3(256), 0, stream,
                       gpT, Wl1, (const float*)nullptr, (const float*)nullptr, bl1, glT);
    hipLaunchKernelGGL(head_c, dim3(1), dim3(320), 0, stream, glT, Wl2, bl2, dout);
    hipLaunchKernelGGL(loss_kernel, dim3(1), dim3(64), 0, stream, scal, dout);
}